// Round 7
// baseline (59.836 us; speedup 1.0000x reference)
//
#include <hip/hip_runtime.h>
#include <hip/hip_bf16.h>

#define T_DIM 2048
#define B_DIM 2
#define E_DIM 256
#define H_DIM 8
#define D_DIM 32
#define M_DIM (T_DIM*B_DIM)   // 4096
#define SPLIT 4
#define S_CHUNK (T_DIM/SPLIT) // 512

typedef __bf16 bf16x8 __attribute__((ext_vector_type(8)));
typedef __bf16 bf16x4 __attribute__((ext_vector_type(4)));
typedef float  f32x4  __attribute__((ext_vector_type(4)));

// ---------------- Kernel 1: fused QKV projection (inline f32->bf16 cvt) ----------------
// grid (64, 12). K and V are written PRE-PERMUTED into MFMA-fragment-linear order:
//   kperm[bh][til][nt][lane]{8}  : lane(lr,lg) holds K[s = til*64+(nt>>1)*32+(lr>>2)*8+(nt&1)*4+(lr&3)][lg*8..+7]
//   vperm[bh][til][j ][lane]{8}  : j=kt*2+dt, lane(lr,lg) holds V^T[d=dt*16+lr][s = til*64+kt*32+lg*8..+7]
__global__ __launch_bounds__(256)
void qkv_kernel(const float* __restrict__ X,
                const float* __restrict__ Wq, const float* __restrict__ Wk, const float* __restrict__ Wv,
                const float* __restrict__ bq, const float* __restrict__ bk, const float* __restrict__ bv,
                __bf16* __restrict__ qh, __bf16* __restrict__ kperm, __bf16* __restrict__ vperm) {
    __shared__ __align__(16) __bf16 Xs[64][136];
    __shared__ __align__(16) __bf16 Ws[64][136];
    const int m0 = blockIdx.x * 64;
    const int which = blockIdx.y >> 2;        // 0 q, 1 k, 2 v
    const int n0 = (blockIdx.y & 3) * 64;
    const float* W = (which == 0) ? Wq : (which == 1) ? Wk : Wv;
    const float* bias = (which == 0) ? bq : (which == 1) ? bk : bv;
    const int tid = threadIdx.x;
    const int wid = tid >> 6, lane = tid & 63;
    const int wm = (wid & 1) * 32, wn = (wid >> 1) * 32;
    const int lr = lane & 15, lg = lane >> 4;

    f32x4 acc[2][2] = {};
    for (int kc = 0; kc < 2; ++kc) {
        for (int c = tid; c < 2048; c += 256) {
            int row = c >> 5, col = (c & 31) * 4;
            float4 xv = *(const float4*)&X[(size_t)(m0 + row) * E_DIM + kc * 128 + col];
            float4 wv = *(const float4*)&W[(size_t)(n0 + row) * E_DIM + kc * 128 + col];
            bf16x4 xb, wb;
            xb[0] = (__bf16)xv.x; xb[1] = (__bf16)xv.y; xb[2] = (__bf16)xv.z; xb[3] = (__bf16)xv.w;
            wb[0] = (__bf16)wv.x; wb[1] = (__bf16)wv.y; wb[2] = (__bf16)wv.z; wb[3] = (__bf16)wv.w;
            *(bf16x4*)&Xs[row][col] = xb;
            *(bf16x4*)&Ws[row][col] = wb;
        }
        __syncthreads();
#pragma unroll
        for (int ks = 0; ks < 4; ++ks) {
            bf16x8 a0 = *(const bf16x8*)&Xs[wm + lr][ks * 32 + lg * 8];
            bf16x8 a1 = *(const bf16x8*)&Xs[wm + 16 + lr][ks * 32 + lg * 8];
            bf16x8 b0 = *(const bf16x8*)&Ws[wn + lr][ks * 32 + lg * 8];
            bf16x8 b1 = *(const bf16x8*)&Ws[wn + 16 + lr][ks * 32 + lg * 8];
            acc[0][0] = __builtin_amdgcn_mfma_f32_16x16x32_bf16(a0, b0, acc[0][0], 0, 0, 0);
            acc[0][1] = __builtin_amdgcn_mfma_f32_16x16x32_bf16(a0, b1, acc[0][1], 0, 0, 0);
            acc[1][0] = __builtin_amdgcn_mfma_f32_16x16x32_bf16(a1, b0, acc[1][0], 0, 0, 0);
            acc[1][1] = __builtin_amdgcn_mfma_f32_16x16x32_bf16(a1, b1, acc[1][1], 0, 0, 0);
        }
        __syncthreads();
    }
    const float scale = 0.17677669529663687f;  // 1/sqrt(32)
#pragma unroll
    for (int mt = 0; mt < 2; ++mt) {
#pragma unroll
        for (int nt = 0; nt < 2; ++nt) {
            int n = n0 + wn + nt * 16 + lr;            // 0..255
            float bb = bias[n];
            int h = n >> 5, d = n & 31;
#pragma unroll
            for (int r = 0; r < 4; ++r) {
                int m = m0 + wm + mt * 16 + lg * 4 + r;
                int t = m >> 1, b = m & 1;
                float v = acc[mt][nt][r] + bb;
                if (which == 0) {
                    v *= scale;
                    qh[((size_t)(b * H_DIM + h) * T_DIM + t) * D_DIM + d] = (__bf16)v;
                } else if (which == 1) {
                    int til = t >> 6, s6 = t & 63;
                    int ntk = ((s6 >> 5) << 1) | ((s6 >> 2) & 1);
                    int lrk = (((s6 >> 3) & 3) << 2) | (s6 & 3);
                    int lanek = ((d >> 3) << 4) | lrk;
                    kperm[((((size_t)(b * H_DIM + h) * 32 + til) * 4 + ntk) * 64 + lanek) * 8 + (d & 7)] = (__bf16)v;
                } else {
                    int til = t >> 6;
                    int ktv = (t >> 5) & 1, lgv = (t >> 3) & 3, elv = t & 7;
                    int jv = ktv * 2 + (d >> 4);
                    int lanev = (lgv << 4) | (d & 15);
                    vperm[((((size_t)(b * H_DIM + h) * 32 + til) * 4 + jv) * 64 + lanev) * 8 + elv] = (__bf16)v;
                }
            }
        }
    }
}

// ---- inline-asm load / wait primitives (T3/T4: counted vmcnt, never 0 mid-loop) ----
#define GLOAD(dst, p) asm volatile("global_load_dwordx4 %0, %1, off" : "=v"(dst) : "v"(p))
#define WAITV8()  asm volatile("s_waitcnt vmcnt(8)" ::: "memory")
#define WAITV0()  asm volatile("s_waitcnt vmcnt(0)" ::: "memory")
#define SBAR()    __builtin_amdgcn_sched_barrier(0)

// one 64-s attention tile: 4 QK MFMA + lane-local exp (fixed cap) + 4 PV MFMA
#define ATTN_TILE(ST, K0, K1, K2, K3, V0, V1, V2, V3) do {                           \
    f32x4 cb0 = *(const f32x4*)&Bs[lr][(ST) * 64 + lg * 8 + 0];                      \
    f32x4 cb1 = *(const f32x4*)&Bs[lr][(ST) * 64 + lg * 8 + 4];                      \
    f32x4 cb2 = *(const f32x4*)&Bs[lr][(ST) * 64 + 32 + lg * 8 + 0];                 \
    f32x4 cb3 = *(const f32x4*)&Bs[lr][(ST) * 64 + 32 + lg * 8 + 4];                 \
    f32x4 sv0 = __builtin_amdgcn_mfma_f32_16x16x32_bf16(K0, qf, cb0, 0, 0, 0);       \
    f32x4 sv1 = __builtin_amdgcn_mfma_f32_16x16x32_bf16(K1, qf, cb1, 0, 0, 0);       \
    f32x4 sv2 = __builtin_amdgcn_mfma_f32_16x16x32_bf16(K2, qf, cb2, 0, 0, 0);       \
    f32x4 sv3 = __builtin_amdgcn_mfma_f32_16x16x32_bf16(K3, qf, cb3, 0, 0, 0);       \
    f32x4 e0, e1, e2, e3;                                                            \
    _Pragma("unroll")                                                                \
    for (int r = 0; r < 4; ++r) {                                                    \
        e0[r] = exp2f(fmaf(sv0[r], LOG2E, NM2));                                     \
        e1[r] = exp2f(fmaf(sv1[r], LOG2E, NM2));                                     \
        e2[r] = exp2f(fmaf(sv2[r], LOG2E, NM2));                                     \
        e3[r] = exp2f(fmaf(sv3[r], LOG2E, NM2));                                     \
    }                                                                                \
    lacc += e0; lacc += e1; lacc += e2; lacc += e3;                                  \
    bf16x8 pf0, pf1;                                                                 \
    _Pragma("unroll")                                                                \
    for (int r = 0; r < 4; ++r) {                                                    \
        pf0[r] = (__bf16)e0[r]; pf0[4 + r] = (__bf16)e1[r];                          \
        pf1[r] = (__bf16)e2[r]; pf1[4 + r] = (__bf16)e3[r];                          \
    }                                                                                \
    o0 = __builtin_amdgcn_mfma_f32_16x16x32_bf16(pf0, V0, o0, 0, 0, 0);              \
    o1 = __builtin_amdgcn_mfma_f32_16x16x32_bf16(pf0, V1, o1, 0, 0, 0);              \
    o0 = __builtin_amdgcn_mfma_f32_16x16x32_bf16(pf1, V2, o0, 0, 0, 0);              \
    o1 = __builtin_amdgcn_mfma_f32_16x16x32_bf16(pf1, V3, o1, 0, 0, 0);              \
} while (0)

// ---------------- Kernel 2: flash attention, bias shared across heads via LDS,
//                  K/V register-double-buffered via inline-asm counted-vmcnt pipeline ----------------
// grid (T/16, B, SPLIT), block 512 = 8 waves; wave w = head w, 16 q-rows, 512-s chunk.
// Inside the loop the ONLY vmem ops are the 8 asm loads/tile -> vmcnt counts are exact:
// at compute of tile t, the 8 loads of tile t+1 are in flight (vmcnt(8)).
__global__ __launch_bounds__(512, 4)
void attn_kernel(const __bf16* __restrict__ qh, const __bf16* __restrict__ kperm,
                 const __bf16* __restrict__ vperm, const float* __restrict__ attn_bias,
                 float* __restrict__ po, float* __restrict__ pl) {
    __shared__ __align__(16) float Bs[16][516];
    const int t0 = blockIdx.x * 16;
    const int b  = blockIdx.y;
    const int sp = blockIdx.z;
    const int tid = threadIdx.x, wid = tid >> 6, lane = tid & 63;
    const int lr = lane & 15, lg = lane >> 4;
    const int bh = b * H_DIM + wid;            // wave = head
    const int sbase = sp * S_CHUNK;
    const int tb0 = sp * 8;
    const float LOG2E = 1.4426950408889634f;
    const float NM2 = -12.0f * LOG2E;          // fixed cap M0 = 12

    // stage bias tile [16][512] f32 once per block (all 8 heads share it)
    {
        const float* bsrc = attn_bias + ((size_t)b * T_DIM + t0) * T_DIM + sbase;
        int r = tid >> 5, c0 = (tid & 31) * 4;
#pragma unroll
        for (int rep = 0; rep < 4; ++rep) {
            float4 v = *(const float4*)&bsrc[(size_t)r * T_DIM + rep * 128 + c0];
            *(float4*)&Bs[r][rep * 128 + c0] = v;
        }
    }
    __syncthreads();   // drains vmcnt -> clean slate for manual counting

    bf16x8 qf = *(const bf16x8*)&qh[((size_t)bh * T_DIM + t0 + lr) * D_DIM + lg * 8];
    const __bf16* kpb = kperm + (size_t)bh * T_DIM * D_DIM + (size_t)lane * 8;
    const __bf16* vpb = vperm + (size_t)bh * T_DIM * D_DIM + (size_t)lane * 8;

    f32x4 o0 = {}, o1 = {};   // o[dt][r]: row t = t0+lg*4+r, col d = dt*16+lr
    f32x4 lacc = {};          // lane-local partial row-sum for q-row t0+lr

    bf16x8 kA0, kA1, kA2, kA3, vA0, vA1, vA2, vA3;
    bf16x8 kB0, kB1, kB2, kB3, vB0, vB1, vB2, vB3;

    // prologue: issue tile tb0 into A-set
    GLOAD(kA0, kpb + (size_t)(tb0 * 4 + 0) * 512);
    GLOAD(kA1, kpb + (size_t)(tb0 * 4 + 1) * 512);
    GLOAD(kA2, kpb + (size_t)(tb0 * 4 + 2) * 512);
    GLOAD(kA3, kpb + (size_t)(tb0 * 4 + 3) * 512);
    GLOAD(vA0, vpb + (size_t)(tb0 * 4 + 0) * 512);
    GLOAD(vA1, vpb + (size_t)(tb0 * 4 + 1) * 512);
    GLOAD(vA2, vpb + (size_t)(tb0 * 4 + 2) * 512);
    GLOAD(vA3, vpb + (size_t)(tb0 * 4 + 3) * 512);

#pragma unroll
    for (int st = 0; st < 8; st += 2) {
        // issue tile st+1 into B-set (8 loads in flight across compute A)
        {
            const int tB = tb0 + st + 1;
            GLOAD(kB0, kpb + (size_t)(tB * 4 + 0) * 512);
            GLOAD(kB1, kpb + (size_t)(tB * 4 + 1) * 512);
            GLOAD(kB2, kpb + (size_t)(tB * 4 + 2) * 512);
            GLOAD(kB3, kpb + (size_t)(tB * 4 + 3) * 512);
            GLOAD(vB0, vpb + (size_t)(tB * 4 + 0) * 512);
            GLOAD(vB1, vpb + (size_t)(tB * 4 + 1) * 512);
            GLOAD(vB2, vpb + (size_t)(tB * 4 + 2) * 512);
            GLOAD(vB3, vpb + (size_t)(tB * 4 + 3) * 512);
        }
        WAITV8();          // A-set complete; B-set (8) still in flight
        SBAR();            // keep MFMAs below the wait
        ATTN_TILE(st, kA0, kA1, kA2, kA3, vA0, vA1, vA2, vA3);

        if (st + 2 < 8) {  // issue tile st+2 into A-set
            const int tA = tb0 + st + 2;
            GLOAD(kA0, kpb + (size_t)(tA * 4 + 0) * 512);
            GLOAD(kA1, kpb + (size_t)(tA * 4 + 1) * 512);
            GLOAD(kA2, kpb + (size_t)(tA * 4 + 2) * 512);
            GLOAD(kA3, kpb + (size_t)(tA * 4 + 3) * 512);
            GLOAD(vA0, vpb + (size_t)(tA * 4 + 0) * 512);
            GLOAD(vA1, vpb + (size_t)(tA * 4 + 1) * 512);
            GLOAD(vA2, vpb + (size_t)(tA * 4 + 2) * 512);
            GLOAD(vA3, vpb + (size_t)(tA * 4 + 3) * 512);
            WAITV8();      // B-set complete; new A-set in flight
        } else {
            WAITV0();      // last tile: drain
        }
        SBAR();
        ATTN_TILE(st + 1, kB0, kB1, kB2, kB3, vB0, vB1, vB2, vB3);
    }

    // row-sum l: horizontal + across the 4 lane-groups (s-partition)
    float l = (lacc[0] + lacc[1]) + (lacc[2] + lacc[3]);
    l += __shfl_xor(l, 16);
    l += __shfl_xor(l, 32);

    // store unnormalized partials
#pragma unroll
    for (int r = 0; r < 4; ++r) {
        int t = t0 + lg * 4 + r;
        size_t rw = ((size_t)bh * T_DIM + t) * SPLIT + sp;
        po[rw * D_DIM + lr]      = o0[r];
        po[rw * D_DIM + 16 + lr] = o1[r];
    }
    if (lg == 0)
        pl[((size_t)bh * T_DIM + t0 + lr) * SPLIT + sp] = l;
}

// ---------------- Kernel 2b: combine split-S partials (equal M0 -> plain sums) ----------------
__global__ __launch_bounds__(256)
void combine_kernel(const float* __restrict__ po, const float* __restrict__ pl,
                    __bf16* __restrict__ attn) {
    int idx = blockIdx.x * 256 + threadIdx.x;
    int row = idx >> 3, dg = idx & 7;
    int bh = row >> 11, t = row & 2047;
    int b = bh >> 3, h = bh & 7;

    float L = 0.f;
    f32x4 acc = {};
#pragma unroll
    for (int s2 = 0; s2 < SPLIT; ++s2) {
        L += pl[(size_t)row * SPLIT + s2];
        f32x4 v = *(const f32x4*)&po[((size_t)row * SPLIT + s2) * D_DIM + dg * 4];
#pragma unroll
        for (int j = 0; j < 4; ++j) acc[j] += v[j];
    }
    float inv = 1.0f / L;
    bf16x4 o4;
#pragma unroll
    for (int j = 0; j < 4; ++j) o4[j] = (__bf16)(acc[j] * inv);
    *(bf16x4*)&attn[((size_t)(t * B_DIM + b)) * E_DIM + h * D_DIM + dg * 4] = o4;
}

// ---------------- Kernel 3: output projection (inline Wo f32->bf16 cvt) ----------------
__global__ __launch_bounds__(256)
void oproj_kernel(const __bf16* __restrict__ X, const float* __restrict__ Wo,
                  const float* __restrict__ bo, float* __restrict__ out) {
    __shared__ __align__(16) __bf16 Xs[64][136];
    __shared__ __align__(16) __bf16 Ws[64][136];
    const int m0 = blockIdx.x * 64;
    const int n0 = blockIdx.y * 64;
    const int tid = threadIdx.x;
    const int wid = tid >> 6, lane = tid & 63;
    const int wm = (wid & 1) * 32, wn = (wid >> 1) * 32;
    const int lr = lane & 15, lg = lane >> 4;

    f32x4 acc[2][2] = {};
    for (int kc = 0; kc < 2; ++kc) {
        for (int c = tid; c < 1024; c += 256) {
            int row = c >> 4, col = (c & 15) * 8;
            *(bf16x8*)&Xs[row][col] = *(const bf16x8*)&X[(size_t)(m0 + row) * E_DIM + kc * 128 + col];
        }
        for (int c = tid; c < 2048; c += 256) {
            int row = c >> 5, col = (c & 31) * 4;
            float4 wv = *(const float4*)&Wo[(size_t)(n0 + row) * E_DIM + kc * 128 + col];
            bf16x4 wb;
            wb[0] = (__bf16)wv.x; wb[1] = (__bf16)wv.y; wb[2] = (__bf16)wv.z; wb[3] = (__bf16)wv.w;
            *(bf16x4*)&Ws[row][col] = wb;
        }
        __syncthreads();
#pragma unroll
        for (int ks = 0; ks < 4; ++ks) {
            bf16x8 a0 = *(const bf16x8*)&Xs[wm + lr][ks * 32 + lg * 8];
            bf16x8 a1 = *(const bf16x8*)&Xs[wm + 16 + lr][ks * 32 + lg * 8];
            bf16x8 b0 = *(const bf16x8*)&Ws[wn + lr][ks * 32 + lg * 8];
            bf16x8 b1 = *(const bf16x8*)&Ws[wn + 16 + lr][ks * 32 + lg * 8];
            acc[0][0] = __builtin_amdgcn_mfma_f32_16x16x32_bf16(a0, b0, acc[0][0], 0, 0, 0);
            acc[0][1] = __builtin_amdgcn_mfma_f32_16x16x32_bf16(a0, b1, acc[0][1], 0, 0, 0);
            acc[1][0] = __builtin_amdgcn_mfma_f32_16x16x32_bf16(a1, b0, acc[1][0], 0, 0, 0);
            acc[1][1] = __builtin_amdgcn_mfma_f32_16x16x32_bf16(a1, b1, acc[1][1], 0, 0, 0);
        }
        __syncthreads();
    }
#pragma unroll
    for (int mt = 0; mt < 2; ++mt) {
#pragma unroll
        for (int nt = 0; nt < 2; ++nt) {
            int n = n0 + wn + nt * 16 + lr;
            float bb = bo[n];
#pragma unroll
            for (int r = 0; r < 4; ++r) {
                int m = m0 + wm + mt * 16 + lg * 4 + r;
                out[(size_t)m * E_DIM + n] = acc[mt][nt][r] + bb;
            }
        }
    }
}

extern "C" void kernel_launch(void* const* d_in, const int* in_sizes, int n_in,
                              void* d_out, int out_size, void* d_ws, size_t ws_size,
                              hipStream_t stream) {
    const float* query     = (const float*)d_in[0];
    const float* attn_bias = (const float*)d_in[1];
    const float* Wq = (const float*)d_in[2];
    const float* bq = (const float*)d_in[3];
    const float* Wk = (const float*)d_in[4];
    const float* bk = (const float*)d_in[5];
    const float* Wv = (const float*)d_in[6];
    const float* bv = (const float*)d_in[7];
    const float* Wo = (const float*)d_in[8];
    const float* bo = (const float*)d_in[9];
    float* out = (float*)d_out;

    char* ws = (char*)d_ws;
    __bf16* qhp  = (__bf16*)(ws);                    // [B][H][T][D] 2 MB
    __bf16* kpp  = (__bf16*)(ws + 2097152);          // kperm 2 MB
    __bf16* vpp  = (__bf16*)(ws + 4194304);          // vperm 2 MB
    __bf16* attn = (__bf16*)(ws + 6291456);          // [M][E] 2 MB
    float*  po   = (float*)(ws + 8388608);           // [BH*T][SPLIT][32] f32 = 16 MB
    float*  pl   = (float*)(ws + 25165824);          // [BH*T][SPLIT] f32 = 0.5 MB

    qkv_kernel<<<dim3(M_DIM / 64, 12), 256, 0, stream>>>(
        query, Wq, Wk, Wv, bq, bk, bv, qhp, kpp, vpp);

    attn_kernel<<<dim3(T_DIM / 16, B_DIM, SPLIT), 512, 0, stream>>>(
        qhp, kpp, vpp, attn_bias, po, pl);
    combine_kernel<<<dim3(B_DIM * H_DIM * T_DIM * 8 / 256), 256, 0, stream>>>(po, pl, attn);

    oproj_kernel<<<dim3(M_DIM / 64, E_DIM / 64), 256, 0, stream>>>(attn, Wo, bo, out);
}